// Round 1
// baseline (195.831 us; speedup 1.0000x reference)
//
#include <hip/hip_runtime.h>

// Light-field disparity cost volume.
// x:   (B=2, C=16, N=25, H=128, W=128) fp32
// out: (B, C, N, D=9, H, W) fp32
// out[b,c,n,di,h,w] = x[b,c,n, h + d*(2 - n/5), w + d*(2 - n%5)], d = di-4,
// zero where shifted indices fall outside [0,128).

constexpr int N_VIEWS = 25;   // 5x5
constexpr int NDISP   = 9;    // -4..4
constexpr int H       = 128;
constexpr int W       = 128;
constexpr int W4      = W / 4;

__global__ __launch_bounds__(256) void build_cost_kernel(
    const float* __restrict__ x, float* __restrict__ out, int total4) {
    int idx = blockIdx.x * blockDim.x + threadIdx.x;
    if (idx >= total4) return;

    // idx -> (bc, n, di, hh, w4)
    int w4 = idx & (W4 - 1);        // 32 float4 per row
    int t  = idx >> 5;
    int hh = t & (H - 1);
    t >>= 7;
    int di = t % NDISP;
    t /= NDISP;
    int n  = t % N_VIEWS;
    int bc = t / N_VIEWS;

    int a1 = n / 5;
    int a2 = n - a1 * 5;
    int d  = di - 4;
    int sh = hh + d * (2 - a1);     // shifted source row
    int dc = d * (2 - a2);          // column shift

    float v[4] = {0.f, 0.f, 0.f, 0.f};
    if ((unsigned)sh < (unsigned)H) {
        const float* src =
            x + ((long long)(bc * N_VIEWS + n) * H + sh) * W;
        int w0 = (w4 << 2) + dc;
        #pragma unroll
        for (int j = 0; j < 4; ++j) {
            int sw = w0 + j;
            if ((unsigned)sw < (unsigned)W) v[j] = src[sw];
        }
    }
    float4 o = make_float4(v[0], v[1], v[2], v[3]);
    reinterpret_cast<float4*>(out)[idx] = o;
}

extern "C" void kernel_launch(void* const* d_in, const int* in_sizes, int n_in,
                              void* d_out, int out_size, void* d_ws, size_t ws_size,
                              hipStream_t stream) {
    const float* x = (const float*)d_in[0];
    float* out = (float*)d_out;
    int total4 = out_size / 4;                      // 29,491,200
    int blocks = (total4 + 255) / 256;              // 115,200
    build_cost_kernel<<<blocks, 256, 0, stream>>>(x, out, total4);
}